// Round 10
// baseline (517.526 us; speedup 1.0000x reference)
//
#include <hip/hip_runtime.h>

#define SEQ 1024
#define NT 256   // 4 waves, 1 wave/SIMD; wave w owns units [32w, 32w+32)

typedef _Float16 half8 __attribute__((ext_vector_type(8)));  // 4 VGPRs
typedef float f32x4 __attribute__((ext_vector_type(4)));     // MFMA 16x16 accum

// h buffer layout (halfwords): [buf][0..127]=h_hi, [buf][160..287]=h_lo.
// lo offset 160 hw = 80 words = bank shift 16 -> a wave's 8 distinct A-read
// addresses (parity x quad) cover all 32 banks exactly once.
#define LO_OFF 160
#define HBUF 320

// Gates use exp2 directly: W_r,W_z,biases pre-scaled by log2e; W_n,bhn,win,bin
// pre-scaled by 2*log2e (tanh(t) = (1-e)/(1+e), e = 2^(-2*log2e*t)).
#define K1 1.44269504f
#define K2 2.88539008f

#define EXP2F(v) __builtin_amdgcn_exp2f(v)   // v_exp_f32: 2^x

__global__ __launch_bounds__(NT, 1)
void gru_kernel(const float* __restrict__ x,     // [B, S, 1]
                const float* __restrict__ w_ih,  // [3H, 1]
                const float* __restrict__ w_hh,  // [3H, H]
                const float* __restrict__ b_ih,  // [3H]
                const float* __restrict__ b_hh,  // [3H]
                const float* __restrict__ w_fc,  // [1, H]
                const float* __restrict__ b_fc,  // [1]
                float* __restrict__ out)         // [B, 1]
{
  __shared__ float xs[SEQ];
  __shared__ __align__(16) _Float16 hs[2][HBUF];
  __shared__ float red[4];

  const int t = threadIdx.x;
  const int b = blockIdx.x;
  const int w = t >> 6;          // wave 0..3
  const int L = t & 63;          // lane
  const int n = L & 15;          // MFMA col within tile == A-row m
  const int quad = L >> 4;       // k-slice; C reg_i = row 4*quad+i
  const int u0 = 32 * w + n;     // first unit this lane covers
  const int u1 = u0 + 16;        // second unit
  const int hl = n & 1;          // A-row parity: even rows = h_hi, odd = h_lo

  // stage x[b,:] (coalesced)
  const float* xrow = x + (size_t)b * SEQ;
  for (int i = t; i < SEQ; i += NT) xs[i] = xrow[i];
  for (int i = t; i < HBUF; i += NT) hs[0][i] = (_Float16)0.f;

  // B fragments (persistent, fp16, pre-scaled): B[k=quad*8+i][col=n]
  // [gate r/z/n][unit-half p][ktile] -> 24 half8 = 96 VGPRs
  half8 Bw[3][2][4];
#pragma unroll
  for (int g = 0; g < 3; ++g) {
    const float scale = (g == 2) ? K2 : K1;
#pragma unroll
    for (int p = 0; p < 2; ++p) {
      const int u = p ? u1 : u0;
      const float* row = w_hh + (size_t)(g * 128 + u) * 128;
#pragma unroll
      for (int kt = 0; kt < 4; ++kt) {
        union { _Float16 s[8]; half8 v; } tmp;
#pragma unroll
        for (int i = 0; i < 8; ++i)
          tmp.s[i] = (_Float16)(row[kt * 32 + quad * 8 + i] * scale);
        Bw[g][p][kt] = tmp.v;
      }
    }
  }
  const float bcr0  = (b_ih[u0] + b_hh[u0]) * K1;
  const float bcr1  = (b_ih[u1] + b_hh[u1]) * K1;
  const float bcz0  = (b_ih[128 + u0] + b_hh[128 + u0]) * K1;
  const float bcz1  = (b_ih[128 + u1] + b_hh[128 + u1]) * K1;
  const float bin0  = b_ih[256 + u0] * K2, bin1 = b_ih[256 + u1] * K2;
  const float bhn0  = b_hh[256 + u0] * K2, bhn1 = b_hh[256 + u1] * K2;
  const float wir0 = w_ih[u0] * K1, wir1 = w_ih[u1] * K1;
  const float wiz0 = w_ih[128 + u0] * K1, wiz1 = w_ih[128 + u1] * K1;
  const float win0 = w_ih[256 + u0] * K2, win1 = w_ih[256 + u1] * K2;

  // per-lane A-read base (halfwords): parity-selected hi/lo bank group
  const int abase = hl * LO_OFF + quad * 8;
  // quad-distributed h write: quad0->u0 hi, quad1->u0 lo, quad2->u1 hi, quad3->u1 lo
  const int waddr = ((quad & 2) ? u1 : u0) + ((quad & 1) ? LO_OFF : 0);

  float h0 = 0.f, h1 = 0.f;   // h[u0], h[u1], replicated across quads
  __syncthreads();

#define MF(A, B, C) C = __builtin_amdgcn_mfma_f32_16x16x32_f16(A, B, C, 0, 0, 0)

  // One step. A even rows = h_hi, odd = h_lo; C reg0 = hi-dot, reg1 = lo-dot,
  // y = C[0]+C[1] in-lane. C[0] pre-loaded with the input-side gi/bias term.
  // Issue order r -> n -> z; the two units' chains interleave.
#define STEP(RD, WR, XT)                                                       \
  {                                                                            \
    const float xt = (XT);                                                     \
    half8 A[4];                                                                \
    _Pragma("unroll")                                                          \
    for (int kt = 0; kt < 4; ++kt)                                             \
      A[kt] = *(const half8*)&hs[RD][abase + kt * 32];                         \
    const float gn0 = fmaf(xt, win0, bin0);                                    \
    const float gn1 = fmaf(xt, win1, bin1);                                    \
    f32x4 ar0, ar1, az0, az1, an0, an1;                                        \
    ar0[0] = fmaf(xt, wir0, bcr0); ar0[1] = 0.f;                               \
    ar1[0] = fmaf(xt, wir1, bcr1); ar1[1] = 0.f;                               \
    an0[0] = bhn0;                 an0[1] = 0.f;                               \
    an1[0] = bhn1;                 an1[1] = 0.f;                               \
    az0[0] = fmaf(xt, wiz0, bcz0); az0[1] = 0.f;                               \
    az1[0] = fmaf(xt, wiz1, bcz1); az1[1] = 0.f;                               \
    _Pragma("unroll")                                                          \
    for (int kt = 0; kt < 4; ++kt) {                                           \
      MF(A[kt], Bw[0][0][kt], ar0);                                            \
      MF(A[kt], Bw[0][1][kt], ar1);                                            \
    }                                                                          \
    const float r0 = __builtin_amdgcn_rcpf(1.f + EXP2F(-(ar0[0] + ar0[1])));   \
    const float r1 = __builtin_amdgcn_rcpf(1.f + EXP2F(-(ar1[0] + ar1[1])));   \
    _Pragma("unroll")                                                          \
    for (int kt = 0; kt < 4; ++kt) {                                           \
      MF(A[kt], Bw[2][0][kt], an0);                                            \
      MF(A[kt], Bw[2][1][kt], an1);                                            \
    }                                                                          \
    const float yn0 = fmaf(r0, an0[0] + an0[1], gn0);                          \
    const float yn1 = fmaf(r1, an1[0] + an1[1], gn1);                          \
    const float e0 = EXP2F(-yn0), e1 = EXP2F(-yn1);                            \
    const float nn0 = (1.f - e0) * __builtin_amdgcn_rcpf(1.f + e0);            \
    const float nn1 = (1.f - e1) * __builtin_amdgcn_rcpf(1.f + e1);            \
    _Pragma("unroll")                                                          \
    for (int kt = 0; kt < 4; ++kt) {                                           \
      MF(A[kt], Bw[1][0][kt], az0);                                            \
      MF(A[kt], Bw[1][1][kt], az1);                                            \
    }                                                                          \
    const float z0 = __builtin_amdgcn_rcpf(1.f + EXP2F(-(az0[0] + az0[1])));   \
    const float z1 = __builtin_amdgcn_rcpf(1.f + EXP2F(-(az1[0] + az1[1])));   \
    h0 = fmaf(z0, h0 - nn0, nn0);                                              \
    h1 = fmaf(z1, h1 - nn1, nn1);                                              \
    const float hsel = (quad & 2) ? h1 : h0;                                   \
    const _Float16 hih = (_Float16)hsel;                                       \
    const _Float16 loh = (_Float16)(hsel - (float)hih);                        \
    hs[WR][waddr] = (quad & 1) ? loh : hih;                                    \
    __syncthreads();                                                           \
  }

  // xt register pipeline: two steps ahead so no fresh LDS read sits on the
  // step-head dependency chain.
  float xa = xs[0], xb = xs[1];
  for (int s = 0; s < SEQ; s += 2) {
    const float xc = (s + 2 < SEQ) ? xs[s + 2] : 0.f;
    const float xd = (s + 2 < SEQ) ? xs[s + 3] : 0.f;
    STEP(0, 1, xa);
    STEP(1, 0, xb);
    xa = xc;
    xb = xd;
  }
#undef STEP
#undef MF

  // epilogue: out[b] = relu(h_T) . w_fc + b_fc
  float v = (quad == 0) ? fmaf(fmaxf(h0, 0.f), w_fc[u0],
                               fmaxf(h1, 0.f) * w_fc[u1]) : 0.f;
#pragma unroll
  for (int off = 1; off < 64; off <<= 1) v += __shfl_xor(v, off);
  if (L == 0) red[w] = v;
  __syncthreads();
  if (t == 0)
    out[b] = red[0] + red[1] + red[2] + red[3] + b_fc[0];
}

extern "C" void kernel_launch(void* const* d_in, const int* in_sizes, int n_in,
                              void* d_out, int out_size, void* d_ws, size_t ws_size,
                              hipStream_t stream) {
  const float* x    = (const float*)d_in[0];
  const float* w_ih = (const float*)d_in[1];
  const float* w_hh = (const float*)d_in[2];
  const float* b_ih = (const float*)d_in[3];
  const float* b_hh = (const float*)d_in[4];
  const float* w_fc = (const float*)d_in[5];
  const float* b_fc = (const float*)d_in[6];
  gru_kernel<<<256, NT, 0, stream>>>(x, w_ih, w_hh, b_ih, b_hh, w_fc, b_fc,
                                     (float*)d_out);
}

// Round 11
// 460.110 us; speedup vs baseline: 1.1248x; 1.1248x over previous
//
#include <hip/hip_runtime.h>

#define SEQ 1024
#define NT 512   // 8 waves; wave w owns gate-preact cols [16w,16w+16) for r,z,n

typedef _Float16 half8 __attribute__((ext_vector_type(8)));  // 4 VGPRs
typedef float f32x4 __attribute__((ext_vector_type(4)));     // MFMA 16x16 accum

// h buffer layout (halfwords): [buf][0..127]=h_hi, [buf][160..287]=h_lo.
// lo offset 160 hw = 80 words = bank shift 16 -> a wave's 8 distinct A-read
// addresses (parity x quad) cover all 32 banks exactly once.
#define LO_OFF 160
#define HBUF 320

// Gates use exp2 directly: W_r,W_z,biases pre-scaled by log2e; W_n,bhn,win,bin
// pre-scaled by 2*log2e (tanh(t) = (1-e)/(1+e), e = 2^(-2*log2e*t)).
#define K1 1.44269504f
#define K2 2.88539008f

#define EXP2F(v) __builtin_amdgcn_exp2f(v)   // v_exp_f32: 2^x

__global__ __launch_bounds__(NT, 2)
void gru_kernel(const float* __restrict__ x,     // [B, S, 1]
                const float* __restrict__ w_ih,  // [3H, 1]
                const float* __restrict__ w_hh,  // [3H, H]
                const float* __restrict__ b_ih,  // [3H]
                const float* __restrict__ b_hh,  // [3H]
                const float* __restrict__ w_fc,  // [1, H]
                const float* __restrict__ b_fc,  // [1]
                float* __restrict__ out)         // [B, 1]
{
  __shared__ float xs[SEQ];
  __shared__ __align__(16) _Float16 hs[2][HBUF];
  __shared__ float red[8];

  const int t = threadIdx.x;
  const int b = blockIdx.x;
  const int w = t >> 6;          // wave 0..7
  const int L = t & 63;          // lane
  const int n = L & 15;          // MFMA col (unit in tile) == A-row m
  const int quad = L >> 4;       // k-slice; C reg_i = row 4*quad+i
  const int u = 16 * w + n;      // hidden unit
  const int hl = n & 1;          // A-row parity: even rows = h_hi, odd = h_lo

  // stage x[b,:] (coalesced)
  const float* xrow = x + (size_t)b * SEQ;
  for (int i = t; i < SEQ; i += NT) xs[i] = xrow[i];
  if (t < HBUF) hs[0][t] = (_Float16)0.f;

  // B fragments (persistent, fp16, pre-scaled): B[k=quad*8+i][col=n]
  half8 Bw[3][4];
#pragma unroll
  for (int g = 0; g < 3; ++g) {
    const float scale = (g == 2) ? K2 : K1;
    const float* row = w_hh + (size_t)(g * 128 + u) * 128;
#pragma unroll
    for (int kt = 0; kt < 4; ++kt) {
      union { _Float16 s[8]; half8 v; } tmp;
#pragma unroll
      for (int i = 0; i < 8; ++i)
        tmp.s[i] = (_Float16)(row[kt * 32 + quad * 8 + i] * scale);
      Bw[g][kt] = tmp.v;
    }
  }
  const float bcr  = (b_ih[u] + b_hh[u]) * K1;
  const float bcz  = (b_ih[128 + u] + b_hh[128 + u]) * K1;
  const float bin2 = b_ih[256 + u] * K2;
  const float bhn2 = b_hh[256 + u] * K2;
  const float wir = w_ih[u] * K1, wiz = w_ih[128 + u] * K1, win2 = w_ih[256 + u] * K2;

  // per-lane A-read base (halfwords): parity-selected hi/lo bank group
  const int abase = hl * LO_OFF + quad * 8;
  // predicated h-write: quad0 stores hi at u, quad1 stores lo at u+LO_OFF
  const int waddr = u + ((quad & 1) ? LO_OFF : 0);

  float hprev = 0.f;   // h[u], replicated across quads (identical math)
  __syncthreads();

#define MF(A, B, C) C = __builtin_amdgcn_mfma_f32_16x16x32_f16(A, B, C, 0, 0, 0)

  // One step. A even rows = h_hi, odd = h_lo; C reg0 = hi-dot, reg1 = lo-dot,
  // y = C[0]+C[1] in-lane. C[0] of the 'a' acc pre-loaded with gi/bias.
  // Split accumulators per gate (kt0-1 vs kt2-3): MFMA dep-chain depth 2.
#define STEP(RD, WR, XT)                                                       \
  {                                                                            \
    const float xt = (XT);                                                     \
    half8 A[4];                                                                \
    _Pragma("unroll")                                                          \
    for (int kt = 0; kt < 4; ++kt)                                             \
      A[kt] = *(const half8*)&hs[RD][abase + kt * 32];                         \
    const float gn = fmaf(xt, win2, bin2);                                     \
    f32x4 ara, arb, aza, azb, ana, anb;                                        \
    ara[0] = fmaf(xt, wir, bcr); ara[1] = 0.f;                                 \
    arb[0] = 0.f;                arb[1] = 0.f;                                 \
    aza[0] = fmaf(xt, wiz, bcz); aza[1] = 0.f;                                 \
    azb[0] = 0.f;                azb[1] = 0.f;                                 \
    ana[0] = bhn2;               ana[1] = 0.f;                                 \
    anb[0] = 0.f;                anb[1] = 0.f;                                 \
    MF(A[0], Bw[0][0], ara); MF(A[2], Bw[0][2], arb);                          \
    MF(A[1], Bw[0][1], ara); MF(A[3], Bw[0][3], arb);                          \
    MF(A[0], Bw[2][0], ana); MF(A[2], Bw[2][2], anb);                          \
    MF(A[1], Bw[2][1], ana); MF(A[3], Bw[2][3], anb);                          \
    MF(A[0], Bw[1][0], aza); MF(A[2], Bw[1][2], azb);                          \
    MF(A[1], Bw[1][1], aza); MF(A[3], Bw[1][3], azb);                          \
    const float yr = (ara[0] + ara[1]) + (arb[0] + arb[1]);                    \
    const float r = __builtin_amdgcn_rcpf(1.f + EXP2F(-yr));                   \
    const float dn2 = (ana[0] + ana[1]) + (anb[0] + anb[1]);                   \
    const float yn = fmaf(r, dn2, gn);                                         \
    const float e = EXP2F(-yn);                                                \
    const float nn = (1.f - e) * __builtin_amdgcn_rcpf(1.f + e);               \
    const float yz = (aza[0] + aza[1]) + (azb[0] + azb[1]);                    \
    const float z = __builtin_amdgcn_rcpf(1.f + EXP2F(-yz));                   \
    hprev = fmaf(z, hprev - nn, nn);                                           \
    const _Float16 hih = (_Float16)hprev;                                      \
    const _Float16 loh = (_Float16)(hprev - (float)hih);                       \
    if (quad < 2) hs[WR][waddr] = (quad & 1) ? loh : hih;                      \
    __syncthreads();                                                           \
  }

  for (int s = 0; s < SEQ; s += 2) {
    const float xt0 = xs[s];
    const float xt1 = xs[s + 1];
    STEP(0, 1, xt0);
    STEP(1, 0, xt1);
  }
#undef STEP
#undef MF

  // epilogue: out[b] = relu(h_T) . w_fc + b_fc
  float v = (quad == 0) ? fmaxf(hprev, 0.f) * w_fc[u] : 0.f;
#pragma unroll
  for (int off = 1; off < 64; off <<= 1) v += __shfl_xor(v, off);
  if (L == 0) red[w] = v;
  __syncthreads();
  if (t == 0) {
    float sum = 0.f;
#pragma unroll
    for (int k = 0; k < 8; ++k) sum += red[k];
    out[b] = sum + b_fc[0];
  }
}

extern "C" void kernel_launch(void* const* d_in, const int* in_sizes, int n_in,
                              void* d_out, int out_size, void* d_ws, size_t ws_size,
                              hipStream_t stream) {
  const float* x    = (const float*)d_in[0];
  const float* w_ih = (const float*)d_in[1];
  const float* w_hh = (const float*)d_in[2];
  const float* b_ih = (const float*)d_in[3];
  const float* b_hh = (const float*)d_in[4];
  const float* w_fc = (const float*)d_in[5];
  const float* b_fc = (const float*)d_in[6];
  gru_kernel<<<256, NT, 0, stream>>>(x, w_ih, w_hh, b_ih, b_hh, w_fc, b_fc,
                                     (float*)d_out);
}